// Round 2
// baseline (7573.739 us; speedup 1.0000x reference)
//
#include <hip/hip_runtime.h>

#define B_ 128
#define T_ 512
#define E_ 256
#define H_ 512
#define NSLICE 16   // h-slices per (dir, bgroup)
#define NBG 4       // batch groups of 32 rows
#define AGENT __HIP_MEMORY_SCOPE_AGENT

typedef float f32x16 __attribute__((ext_vector_type(16)));
typedef unsigned short u16x8 __attribute__((ext_vector_type(8)));
typedef __bf16 bf16x8 __attribute__((ext_vector_type(8)));

union U8 { u16x8 u; bf16x8 b; unsigned d[4]; };

__device__ __forceinline__ unsigned short f2bf(float f) {
    unsigned u = __float_as_uint(f);
    return (unsigned short)((u + 0x7FFFu + ((u >> 16) & 1u)) >> 16);
}
__device__ __forceinline__ float bf2f(unsigned short s) {
    return __uint_as_float(((unsigned)s) << 16);
}
__device__ __forceinline__ float sigm(float x) { return 1.f / (1.f + __expf(-x)); }
__device__ __forceinline__ float tanh_f(float x) {
    float e = __expf(2.f * x);
    return 1.f - 2.f / (e + 1.f);   // inf-safe at both ends
}

// ---------------- gather: x_bf16[b][t][e] = bf16(emb[inputs[b][t]][e]) --------
__global__ void gather_k(const int* __restrict__ idx, const float* __restrict__ emb,
                         unsigned short* __restrict__ x) {
    int row = blockIdx.x;          // b*T + t
    int e = threadIdx.x;           // 0..255
    int id = idx[row];
    x[row * E_ + e] = f2bf(emb[id * E_ + e]);
}

// ---------------- persistent bidirectional GRU ----------------
// grid: 128 WGs = dir(2) x bgroup(4) x slice(16); 192 threads = 3 waves (r,z,n)
// h-exchange: fence-free. h words + flags are all relaxed agent-scope accesses
// (sc0 sc1 -> LLC, the cross-XCD coherence point). NO acquire/release fences:
// agent acquire/release would emit buffer_inv / buffer_wbl2 (full L2
// invalidate/writeback) every step — that was R0's 780 MB HBM re-fetch and
// the ~12 us/step critical path.
__global__ __launch_bounds__(192, 1) void gru_k(
    const unsigned short* __restrict__ x,
    const float* __restrict__ Wih_f, const float* __restrict__ Whh_f,
    const float* __restrict__ bih_f, const float* __restrict__ bhh_f,
    const float* __restrict__ Wih_b, const float* __restrict__ Whh_b,
    const float* __restrict__ bih_b, const float* __restrict__ bhh_b,
    unsigned short* __restrict__ hbuf,   // [2 dirs][2 bufs][128][512] bf16
    unsigned int* __restrict__ cnt)      // [2][4][T+1]
{
    const int wg  = blockIdx.x;
    const int dir = wg >> 6;          // 0 fwd, 1 bwd
    const int bg  = (wg >> 4) & 3;
    const int sl  = wg & 15;
    const int wid = threadIdx.x >> 6;   // 0=r 1=z 2=n
    const int lane = threadIdx.x & 63;
    const int l31 = lane & 31;
    const int lh  = lane >> 5;          // 0/1

    const float* Wih = dir ? Wih_b : Wih_f;
    const float* Whh = dir ? Whh_b : Whh_f;
    const float* bih = dir ? bih_b : bih_f;
    const float* bhh = dir ? bhh_b : bhh_f;

    // W row this lane serves (B-operand col): gate block + slice + lane col
    const int gcol = wid * H_ + sl * 32 + l31;

    // ---- load persistent B-fragments: 48 x (16B/lane) = 192 VGPRs ----
    U8 Bf[48];
#pragma unroll
    for (int c = 0; c < 16; ++c) {               // x-part K=0..255
        const float* p = Wih + gcol * E_ + c * 16 + 8 * lh;
        float4 a = *(const float4*)p;
        float4 b = *(const float4*)(p + 4);
        U8 v;
        v.u[0] = f2bf(a.x); v.u[1] = f2bf(a.y); v.u[2] = f2bf(a.z); v.u[3] = f2bf(a.w);
        v.u[4] = f2bf(b.x); v.u[5] = f2bf(b.y); v.u[6] = f2bf(b.z); v.u[7] = f2bf(b.w);
        Bf[c] = v;
    }
#pragma unroll
    for (int c = 0; c < 32; ++c) {               // h-part K=256..767
        const float* p = Whh + gcol * H_ + c * 16 + 8 * lh;
        float4 a = *(const float4*)p;
        float4 b = *(const float4*)(p + 4);
        U8 v;
        v.u[0] = f2bf(a.x); v.u[1] = f2bf(a.y); v.u[2] = f2bf(a.z); v.u[3] = f2bf(a.w);
        v.u[4] = f2bf(b.x); v.u[5] = f2bf(b.y); v.u[6] = f2bf(b.z); v.u[7] = f2bf(b.w);
        Bf[16 + c] = v;
    }

    const float bi = bih[gcol];
    const float bh = bhh[gcol];

    const int b = bg * 32 + l31;                 // A-operand row (batch)
    const unsigned short* xrow = x + (b * T_) * E_;
    unsigned short* hb = hbuf + dir * (2 * B_ * H_);
    unsigned int* cn = cnt + (dir * NBG + bg) * (T_ + 1);

    __shared__ float lds_r[2][16][64];
    __shared__ float lds_z[2][16][64];

    f32x16 hold;                                 // n-wave: own h slice, f32
#pragma unroll
    for (int i = 0; i < 16; ++i) hold[i] = 0.f;

    for (int t = 0; t < T_; ++t) {
        const int tx = dir ? (T_ - 1 - t) : t;
        const int p = t & 1;

        f32x16 acc, acc2;                        // acc: x-part (+b_ih), acc2: h-part (+b_hh)
#pragma unroll
        for (int i = 0; i < 16; ++i) { acc[i] = bi; acc2[i] = bh; }

        // x-part: independent of sync — issue & compute first
        {
            const unsigned short* xp = xrow + tx * E_;
            U8 ax[16];
#pragma unroll
            for (int c = 0; c < 16; ++c) ax[c].u = *(const u16x8*)(xp + c * 16 + 8 * lh);
#pragma unroll
            for (int c = 0; c < 16; ++c)
                acc = __builtin_amdgcn_mfma_f32_32x32x16_bf16(ax[c].b, Bf[c].b, acc, 0, 0, 0);
        }

        if (t > 0) {
            // wait for all 16 slice-producers of previous step (relaxed; no fence)
            while (__hip_atomic_load(cn + t, __ATOMIC_RELAXED, AGENT) < NSLICE)
                __builtin_amdgcn_s_sleep(1);
            asm volatile("" ::: "memory");       // compiler barrier: keep h loads below

            // h loads: relaxed agent-scope dword atomics -> global_load_dword sc0 sc1
            // (read the LLC coherence point directly; no L2 invalidate needed)
            const unsigned short* hp = hb + ((t & 1) * B_ + b) * H_;
            U8 ah[32];
#pragma unroll
            for (int c = 0; c < 32; ++c) {
                const unsigned* pw = (const unsigned*)(hp + c * 16 + 8 * lh);
#pragma unroll
                for (int w = 0; w < 4; ++w)
                    ah[c].d[w] = __hip_atomic_load(pw + w, __ATOMIC_RELAXED, AGENT);
            }
#pragma unroll
            for (int c = 0; c < 32; ++c)
                acc2 = __builtin_amdgcn_mfma_f32_32x32x16_bf16(ah[c].b, Bf[16 + c].b, acc2, 0, 0, 0);
        }

        // gates: r,z waves publish to LDS; n wave does the update
        if (wid == 0) {
#pragma unroll
            for (int i = 0; i < 16; ++i) lds_r[p][i][lane] = sigm(acc[i] + acc2[i]);
        } else if (wid == 1) {
#pragma unroll
            for (int i = 0; i < 16; ++i) lds_z[p][i][lane] = sigm(acc[i] + acc2[i]);
        }
        __syncthreads();
        if (wid == 2) {
            unsigned short* hw = hb + (((t + 1) & 1) * B_) * H_;
#pragma unroll
            for (int i = 0; i < 16; ++i) {
                float r = lds_r[p][i][lane];
                float z = lds_z[p][i][lane];
                float n = tanh_f(acc[i] + r * acc2[i]);   // xn + r*(hn+b_hh_n)
                float hn = (1.f - z) * n + z * hold[i];
                hold[i] = hn;
                int row = bg * 32 + (i & 3) + 8 * (i >> 2) + 4 * lh;  // C/D row map
                // relaxed agent-scope store -> global_store_short sc0 sc1 (to LLC)
                __hip_atomic_store(&hw[row * H_ + sl * 32 + l31], f2bf(hn),
                                   __ATOMIC_RELAXED, AGENT);
            }
            // order: all h stores acked at the coherence point BEFORE flag bump.
            // vmcnt counts stores; sc1 stores ack from LLC.
            asm volatile("s_waitcnt vmcnt(0)" ::: "memory");
            if (lane == 0)
                __hip_atomic_fetch_add(cn + t + 1, 1u, __ATOMIC_RELAXED, AGENT);
        }
    }
}

// ---------------- FC head: out[b] = sigmoid(concat(h_f,h_b) . fc_w + fc_b) ----
__global__ void fc_k(const unsigned short* __restrict__ hbuf,
                     const float* __restrict__ fcw, const float* __restrict__ fcb,
                     float* __restrict__ out) {
    int bb = blockIdx.x;
    int l = threadIdx.x;       // 64 threads = 1 wave
    float s = 0.f;
    for (int j = l; j < H_; j += 64) {
        s += bf2f(hbuf[bb * H_ + j]) * fcw[j];                       // fwd, buf 0
        s += bf2f(hbuf[2 * B_ * H_ + bb * H_ + j]) * fcw[H_ + j];    // bwd, buf 0
    }
#pragma unroll
    for (int o = 32; o > 0; o >>= 1) s += __shfl_down(s, o);
    if (l == 0) out[bb] = sigm(s + fcb[0]);
}

extern "C" void kernel_launch(void* const* d_in, const int* in_sizes, int n_in,
                              void* d_out, int out_size, void* d_ws, size_t ws_size,
                              hipStream_t stream) {
    (void)in_sizes; (void)n_in; (void)out_size; (void)ws_size;
    const int*   inputs = (const int*)d_in[0];
    const float* emb    = (const float*)d_in[1];
    const float* Wih_f  = (const float*)d_in[2];
    const float* Whh_f  = (const float*)d_in[3];
    const float* bih_f  = (const float*)d_in[4];
    const float* bhh_f  = (const float*)d_in[5];
    const float* Wih_b  = (const float*)d_in[6];
    const float* Whh_b  = (const float*)d_in[7];
    const float* bih_b  = (const float*)d_in[8];
    const float* bhh_b  = (const float*)d_in[9];
    const float* fcw    = (const float*)d_in[10];
    const float* fcb    = (const float*)d_in[11];
    float* out = (float*)d_out;

    char* w = (char*)d_ws;
    unsigned short* xbuf = (unsigned short*)w;                          // 33,554,432 B
    unsigned short* hbuf = (unsigned short*)(w + 33554432);             //    524,288 B
    unsigned int*   cnt  = (unsigned int*)(w + 33554432 + 524288);      //     16,416 B

    hipMemsetAsync(cnt, 0, 2 * NBG * (T_ + 1) * sizeof(unsigned int), stream);
    gather_k<<<B_ * T_, E_, 0, stream>>>(inputs, emb, xbuf);
    gru_k<<<128, 192, 0, stream>>>(xbuf, Wih_f, Whh_f, bih_f, bhh_f,
                                   Wih_b, Whh_b, bih_b, bhh_b, hbuf, cnt);
    fc_k<<<B_, 64, 0, stream>>>(hbuf, fcw, fcb, out);
}

// Round 4
// 4779.141 us; speedup vs baseline: 1.5847x; 1.5847x over previous
//
#include <hip/hip_runtime.h>

#define B_ 128
#define T_ 512
#define E_ 256
#define H_ 512
#define NSLICE 16   // h-slices per (dir, bgroup)
#define NBG 4       // batch groups of 32 rows
#define AGENT __HIP_MEMORY_SCOPE_AGENT

typedef float f32x16 __attribute__((ext_vector_type(16)));
typedef unsigned short u16x8 __attribute__((ext_vector_type(8)));
typedef __bf16 bf16x8 __attribute__((ext_vector_type(8)));
typedef int i32x4 __attribute__((ext_vector_type(4)));

union U8 { u16x8 u; bf16x8 b; i32x4 d; };

__device__ __forceinline__ unsigned short f2bf(float f) {
    unsigned u = __float_as_uint(f);
    return (unsigned short)((u + 0x7FFFu + ((u >> 16) & 1u)) >> 16);
}
__device__ __forceinline__ float bf2f(unsigned short s) {
    return __uint_as_float(((unsigned)s) << 16);
}
__device__ __forceinline__ float sigm(float x) { return 1.f / (1.f + __expf(-x)); }
__device__ __forceinline__ float tanh_f(float x) {
    float e = __expf(2.f * x);
    return 1.f - 2.f / (e + 1.f);   // inf-safe at both ends
}

// hbuf frag-major layout (shorts): [dir][buf][bg][c:32][lane:64][j:8]
// element (dir,buf,bg, batch row b=bg*32+rr, col k) lives at
//   c=k>>4, lane=((k>>3)&1)*32+rr, j=k&7
__device__ __forceinline__ int hfm_base(int dir, int buf, int bg) {
    return ((dir * 2 + buf) * NBG + bg) * (32 * 64 * 8);
}

// ---------------- gather: x_bf16[b][t][e] = bf16(emb[inputs[b][t]][e]) --------
__global__ void gather_k(const int* __restrict__ idx, const float* __restrict__ emb,
                         unsigned short* __restrict__ x) {
    int row = blockIdx.x;          // b*T + t
    int e = threadIdx.x;           // 0..255
    int id = idx[row];
    x[row * E_ + e] = f2bf(emb[id * E_ + e]);
}

// ---------------- persistent bidirectional GRU ----------------
// grid: 128 WGs = dir(2) x bgroup(4) x slice(16); 192 threads = 3 waves (r,z,n)
// Producer side: relaxed agent-scope short stores (compiler-tracked; proven R1)
//   + asm vmcnt(0) + relaxed flag add.
// Consumer side: poll via one self-contained asm LLC load (sc0 sc1 + in-asm
//   waitcnt -> no stale-L2 spin, no operand-lifetime hazard), then an ACQUIRE
//   atomic load (emits buffer_inv -> L1/L2 fresh), then plain coalesced
//   dwordx4 loads (compiler-tracked; proven R0 post-inv).
__global__ __launch_bounds__(192, 1) void gru_k(
    const unsigned short* __restrict__ x,
    const float* __restrict__ Wih_f, const float* __restrict__ Whh_f,
    const float* __restrict__ bih_f, const float* __restrict__ bhh_f,
    const float* __restrict__ Wih_b, const float* __restrict__ Whh_b,
    const float* __restrict__ bih_b, const float* __restrict__ bhh_b,
    unsigned short* __restrict__ hbuf,   // frag-major, 512 KB
    unsigned int* __restrict__ cnt)      // [2][4][T+1]
{
    const int wg  = blockIdx.x;
    const int dir = wg >> 6;          // 0 fwd, 1 bwd
    const int bg  = (wg >> 4) & 3;
    const int sl  = wg & 15;
    const int wid = threadIdx.x >> 6;   // 0=r 1=z 2=n
    const int lane = threadIdx.x & 63;
    const int l31 = lane & 31;
    const int lh  = lane >> 5;          // 0/1

    const float* Wih = dir ? Wih_b : Wih_f;
    const float* Whh = dir ? Whh_b : Whh_f;
    const float* bih = dir ? bih_b : bih_f;
    const float* bhh = dir ? bhh_b : bhh_f;

    // W row this lane serves (B-operand col): gate block + slice + lane col
    const int gcol = wid * H_ + sl * 32 + l31;

    // ---- load persistent B-fragments: 48 x (16B/lane) = 192 VGPRs ----
    U8 Bf[48];
#pragma unroll
    for (int c = 0; c < 16; ++c) {               // x-part K=0..255
        const float* p = Wih + gcol * E_ + c * 16 + 8 * lh;
        float4 a = *(const float4*)p;
        float4 b = *(const float4*)(p + 4);
        U8 v;
        v.u[0] = f2bf(a.x); v.u[1] = f2bf(a.y); v.u[2] = f2bf(a.z); v.u[3] = f2bf(a.w);
        v.u[4] = f2bf(b.x); v.u[5] = f2bf(b.y); v.u[6] = f2bf(b.z); v.u[7] = f2bf(b.w);
        Bf[c] = v;
    }
#pragma unroll
    for (int c = 0; c < 32; ++c) {               // h-part K=256..767
        const float* p = Whh + gcol * H_ + c * 16 + 8 * lh;
        float4 a = *(const float4*)p;
        float4 b = *(const float4*)(p + 4);
        U8 v;
        v.u[0] = f2bf(a.x); v.u[1] = f2bf(a.y); v.u[2] = f2bf(a.z); v.u[3] = f2bf(a.w);
        v.u[4] = f2bf(b.x); v.u[5] = f2bf(b.y); v.u[6] = f2bf(b.z); v.u[7] = f2bf(b.w);
        Bf[16 + c] = v;
    }

    const float bi = bih[gcol];
    const float bh = bhh[gcol];

    const int b = bg * 32 + l31;                 // A-operand row (batch)
    const unsigned short* xrow = x + (b * T_) * E_;
    unsigned int* cn = cnt + (dir * NBG + bg) * (T_ + 1);

    unsigned short* hfm[2] = { hbuf + hfm_base(dir, 0, bg), hbuf + hfm_base(dir, 1, bg) };

    __shared__ float lds_r[2][16][64];
    __shared__ float lds_z[2][16][64];

    f32x16 hold;                                 // n-wave: own h slice, f32
#pragma unroll
    for (int i = 0; i < 16; ++i) hold[i] = 0.f;

    for (int t = 0; t < T_; ++t) {
        const int tx = dir ? (T_ - 1 - t) : t;
        const int p = t & 1;

        f32x16 acc, acc2;                        // acc: x-part (+b_ih), acc2: h-part (+b_hh)
#pragma unroll
        for (int i = 0; i < 16; ++i) { acc[i] = bi; acc2[i] = bh; }

        // x-part first: loads + MFMAs have no h dependency -> overlap the poll
        {
            const unsigned short* xp = xrow + tx * E_;
            U8 ax[16];
#pragma unroll
            for (int c = 0; c < 16; ++c) ax[c].u = *(const u16x8*)(xp + c * 16 + 8 * lh);
#pragma unroll
            for (int c = 0; c < 16; ++c)
                acc = __builtin_amdgcn_mfma_f32_32x32x16_bf16(ax[c].b, Bf[c].b, acc, 0, 0, 0);
        }

        if (t > 0) {
            // poll: LLC-direct read (sc0 sc1). Self-contained asm block: the
            // waitcnt is inside, so no operand outlives the asm -> no VMEM
            // operand-lifetime hazard. Avoids spinning on a stale L2 line.
            for (;;) {
                unsigned v;
                asm volatile("global_load_dword %0, %1, off sc0 sc1\n\t"
                             "s_waitcnt vmcnt(0)"
                             : "=v"(v) : "v"(cn + t) : "memory");
                if (v >= NSLICE) break;
                __builtin_amdgcn_s_sleep(1);
            }
            // acquire: buffer_inv so the plain loads below read fresh LLC data
            (void)__hip_atomic_load(cn + t, __ATOMIC_ACQUIRE, AGENT);

            // h A-frags: plain coalesced dwordx4 (compiler hazard-tracked)
            const unsigned short* hsrc = hfm[p];
#pragma unroll
            for (int c = 0; c < 32; ++c) {
                U8 ah; ah.d = *(const i32x4*)(hsrc + c * 512 + lane * 8);
                acc2 = __builtin_amdgcn_mfma_f32_32x32x16_bf16(ah.b, Bf[16 + c].b, acc2, 0, 0, 0);
            }
        }

        // gates: r,z waves publish to LDS; n wave does the update
        if (wid == 0) {
#pragma unroll
            for (int i = 0; i < 16; ++i) lds_r[p][i][lane] = sigm(acc[i] + acc2[i]);
        } else if (wid == 1) {
#pragma unroll
            for (int i = 0; i < 16; ++i) lds_z[p][i][lane] = sigm(acc[i] + acc2[i]);
        }
        __syncthreads();
        if (wid == 2) {
            // dest: frag-major position of (row = bg*32+rr, col = sl*32+l31)
            unsigned short* sb = hfm[(t + 1) & 1]
                               + (sl * 2 + (l31 >> 4)) * 512
                               + ((l31 >> 3) & 1) * 256 + (l31 & 7);
#pragma unroll
            for (int i = 0; i < 16; ++i) {
                float r = lds_r[p][i][lane];
                float z = lds_z[p][i][lane];
                float n = tanh_f(acc[i] + r * acc2[i]);   // xn + r*(hn+b_hh_n)
                float hn = (1.f - z) * n + z * hold[i];
                hold[i] = hn;
                int rr = (i & 3) + 8 * (i >> 2) + 4 * lh;  // C/D row map
                __hip_atomic_store(sb + rr * 8, f2bf(hn), __ATOMIC_RELAXED, AGENT);
            }
            // all h stores acked at the LLC before the flag bump
            asm volatile("s_waitcnt vmcnt(0)" ::: "memory");
            if (lane == 0)
                __hip_atomic_fetch_add(cn + t + 1, 1u, __ATOMIC_RELAXED, AGENT);
        }
    }
}

// ---------------- FC head: out[b] = sigmoid(concat(h_f,h_b) . fc_w + fc_b) ----
__global__ void fc_k(const unsigned short* __restrict__ hbuf,
                     const float* __restrict__ fcw, const float* __restrict__ fcb,
                     float* __restrict__ out) {
    int bb = blockIdx.x;
    int l = threadIdx.x;       // 64 threads = 1 wave
    int bg = bb >> 5, rr = bb & 31;
    float s = 0.f;
    for (int col = l; col < H_; col += 64) {
        int c = col >> 4, hi = (col >> 3) & 1, j = col & 7;
        int off = c * 512 + (hi * 32 + rr) * 8 + j;
        s += bf2f(hbuf[hfm_base(0, 0, bg) + off]) * fcw[col];        // fwd, buf 0
        s += bf2f(hbuf[hfm_base(1, 0, bg) + off]) * fcw[H_ + col];   // bwd, buf 0
    }
#pragma unroll
    for (int o = 32; o > 0; o >>= 1) s += __shfl_down(s, o);
    if (l == 0) out[bb] = sigm(s + fcb[0]);
}

extern "C" void kernel_launch(void* const* d_in, const int* in_sizes, int n_in,
                              void* d_out, int out_size, void* d_ws, size_t ws_size,
                              hipStream_t stream) {
    (void)in_sizes; (void)n_in; (void)out_size; (void)ws_size;
    const int*   inputs = (const int*)d_in[0];
    const float* emb    = (const float*)d_in[1];
    const float* Wih_f  = (const float*)d_in[2];
    const float* Whh_f  = (const float*)d_in[3];
    const float* bih_f  = (const float*)d_in[4];
    const float* bhh_f  = (const float*)d_in[5];
    const float* Wih_b  = (const float*)d_in[6];
    const float* Whh_b  = (const float*)d_in[7];
    const float* bih_b  = (const float*)d_in[8];
    const float* bhh_b  = (const float*)d_in[9];
    const float* fcw    = (const float*)d_in[10];
    const float* fcb    = (const float*)d_in[11];
    float* out = (float*)d_out;

    char* w = (char*)d_ws;
    unsigned short* xbuf = (unsigned short*)w;                          // 33,554,432 B
    unsigned short* hbuf = (unsigned short*)(w + 33554432);             //    524,288 B
    unsigned int*   cnt  = (unsigned int*)(w + 33554432 + 524288);      //     16,416 B

    hipMemsetAsync(cnt, 0, 2 * NBG * (T_ + 1) * sizeof(unsigned int), stream);
    gather_k<<<B_ * T_, E_, 0, stream>>>(inputs, emb, xbuf);
    gru_k<<<128, 192, 0, stream>>>(xbuf, Wih_f, Whh_f, bih_f, bhh_f,
                                   Wih_b, Whh_b, bih_b, bhh_b, hbuf, cnt);
    fc_k<<<B_, 64, 0, stream>>>(hbuf, fcw, fcb, out);
}

// Round 5
// 4590.364 us; speedup vs baseline: 1.6499x; 1.0411x over previous
//
#include <hip/hip_runtime.h>

#define B_ 128
#define T_ 512
#define E_ 256
#define H_ 512
#define NSLICE 16   // h-slices per (dir, bgroup)
#define NBG 4       // batch groups of 32 rows
#define AGENT __HIP_MEMORY_SCOPE_AGENT

typedef float f32x16 __attribute__((ext_vector_type(16)));
typedef unsigned short u16x8 __attribute__((ext_vector_type(8)));
typedef __bf16 bf16x8 __attribute__((ext_vector_type(8)));
typedef int i32x4 __attribute__((ext_vector_type(4)));

union U8 { u16x8 u; bf16x8 b; i32x4 d; };

__device__ __forceinline__ unsigned short f2bf(float f) {
    unsigned u = __float_as_uint(f);
    return (unsigned short)((u + 0x7FFFu + ((u >> 16) & 1u)) >> 16);
}
__device__ __forceinline__ float bf2f(unsigned short s) {
    return __uint_as_float(((unsigned)s) << 16);
}
__device__ __forceinline__ float sigm(float x) { return 1.f / (1.f + __expf(-x)); }
__device__ __forceinline__ float tanh_f(float x) {
    float e = __expf(2.f * x);
    return 1.f - 2.f / (e + 1.f);   // inf-safe at both ends
}

// hbuf frag-major layout (shorts): [dir][buf][bg][c:32][lane:64][j:8]
// element (dir,buf,bg, batch row b=bg*32+rr, col k) lives at
//   c=k>>4, lane=((k>>3)&1)*32+rr, j=k&7
__device__ __forceinline__ int hfm_base(int dir, int buf, int bg) {
    return ((dir * 2 + buf) * NBG + bg) * (32 * 64 * 8);
}

// ---------------- gather: x_bf16[b][t][e] = bf16(emb[inputs[b][t]][e]) --------
__global__ void gather_k(const int* __restrict__ idx, const float* __restrict__ emb,
                         unsigned short* __restrict__ x) {
    int row = blockIdx.x;          // b*T + t
    int e = threadIdx.x;           // 0..255
    int id = idx[row];
    x[row * E_ + e] = f2bf(emb[id * E_ + e]);
}

// ---------------- persistent bidirectional GRU ----------------
// grid: 128 WGs = dir(2) x bgroup(4) x slice(16); 192 threads = 3 waves (r,z,n)
// Sync per step:
//   producer (n-wave): coalesced-ish relaxed short stores -> vmcnt(0) ->
//     ONE relaxed flag STORE of value t+1 (64B-stride word per slice; no RMW).
//   consumer: ONLY wid0 polls (one self-contained asm gather of the 16 flag
//     words, __any(v<t) retry), then one acquire-load (buffer_inv), then
//     __syncthreads releases wid1/wid2 -> plain coalesced h loads (L2 fresh).
__global__ __launch_bounds__(192, 1) void gru_k(
    const unsigned short* __restrict__ x,
    const float* __restrict__ Wih_f, const float* __restrict__ Whh_f,
    const float* __restrict__ bih_f, const float* __restrict__ bhh_f,
    const float* __restrict__ Wih_b, const float* __restrict__ Whh_b,
    const float* __restrict__ bih_b, const float* __restrict__ bhh_b,
    unsigned short* __restrict__ hbuf,   // frag-major, 512 KB
    unsigned int* __restrict__ flags)    // [2][4][16] words, 64B stride
{
    const int wg  = blockIdx.x;
    const int dir = wg >> 6;          // 0 fwd, 1 bwd
    const int bg  = (wg >> 4) & 3;
    const int sl  = wg & 15;
    const int wid = threadIdx.x >> 6;   // 0=r 1=z 2=n
    const int lane = threadIdx.x & 63;
    const int l31 = lane & 31;
    const int lh  = lane >> 5;          // 0/1

    const float* Wih = dir ? Wih_b : Wih_f;
    const float* Whh = dir ? Whh_b : Whh_f;
    const float* bih = dir ? bih_b : bih_f;
    const float* bhh = dir ? bhh_b : bhh_f;

    // W row this lane serves (B-operand col): gate block + slice + lane col
    const int gcol = wid * H_ + sl * 32 + l31;

    // ---- load persistent B-fragments: 48 x (16B/lane) = 192 VGPRs ----
    U8 Bf[48];
#pragma unroll
    for (int c = 0; c < 16; ++c) {               // x-part K=0..255
        const float* p = Wih + gcol * E_ + c * 16 + 8 * lh;
        float4 a = *(const float4*)p;
        float4 b = *(const float4*)(p + 4);
        U8 v;
        v.u[0] = f2bf(a.x); v.u[1] = f2bf(a.y); v.u[2] = f2bf(a.z); v.u[3] = f2bf(a.w);
        v.u[4] = f2bf(b.x); v.u[5] = f2bf(b.y); v.u[6] = f2bf(b.z); v.u[7] = f2bf(b.w);
        Bf[c] = v;
    }
#pragma unroll
    for (int c = 0; c < 32; ++c) {               // h-part K=256..767
        const float* p = Whh + gcol * H_ + c * 16 + 8 * lh;
        float4 a = *(const float4*)p;
        float4 b = *(const float4*)(p + 4);
        U8 v;
        v.u[0] = f2bf(a.x); v.u[1] = f2bf(a.y); v.u[2] = f2bf(a.z); v.u[3] = f2bf(a.w);
        v.u[4] = f2bf(b.x); v.u[5] = f2bf(b.y); v.u[6] = f2bf(b.z); v.u[7] = f2bf(b.w);
        Bf[16 + c] = v;
    }

    const float bi = bih[gcol];
    const float bh = bhh[gcol];

    const int b = bg * 32 + l31;                 // A-operand row (batch)
    const unsigned short* xrow = x + (b * T_) * E_;

    unsigned int* fgrp = flags + (dir * NBG + bg) * 16 * 16;   // 64B-stride words
    const unsigned int* fpoll = fgrp + (lane & 15) * 16;       // wid0 gather addr
    unsigned int* fmine = fgrp + sl * 16;                      // producer's word

    unsigned short* hfm[2] = { hbuf + hfm_base(dir, 0, bg), hbuf + hfm_base(dir, 1, bg) };

    __shared__ float lds_r[2][16][64];
    __shared__ float lds_z[2][16][64];

    f32x16 hold;                                 // n-wave: own h slice, f32
#pragma unroll
    for (int i = 0; i < 16; ++i) hold[i] = 0.f;

    for (int t = 0; t < T_; ++t) {
        const int tx = dir ? (T_ - 1 - t) : t;
        const int p = t & 1;

        // split accumulators: halve the exposed dependent-MFMA latency
        f32x16 acc, accB, acc2, acc2b;
#pragma unroll
        for (int i = 0; i < 16; ++i) { acc[i] = bi; accB[i] = 0.f; acc2[i] = bh; acc2b[i] = 0.f; }

        // x-part first: loads + MFMAs have no h dependency -> overlap the poll
        {
            const unsigned short* xp = xrow + tx * E_;
            U8 ax[16];
#pragma unroll
            for (int c = 0; c < 16; ++c) ax[c].u = *(const u16x8*)(xp + c * 16 + 8 * lh);
#pragma unroll
            for (int c = 0; c < 16; c += 2) {
                acc  = __builtin_amdgcn_mfma_f32_32x32x16_bf16(ax[c].b,     Bf[c].b,     acc,  0, 0, 0);
                accB = __builtin_amdgcn_mfma_f32_32x32x16_bf16(ax[c + 1].b, Bf[c + 1].b, accB, 0, 0, 0);
            }
        }

        if (t > 0) {
            if (wid == 0) {
                // poll: one LLC gather of the 16 flag words (self-contained asm)
                for (;;) {
                    unsigned v;
                    asm volatile("global_load_dword %0, %1, off sc0 sc1\n\t"
                                 "s_waitcnt vmcnt(0)"
                                 : "=v"(v) : "v"(fpoll) : "memory");
                    if (!__any((int)v < t)) break;
                    __builtin_amdgcn_s_sleep(1);
                }
                // acquire: buffer_inv so plain loads below read fresh data
                (void)__hip_atomic_load(fpoll, __ATOMIC_ACQUIRE, AGENT);
            }
            __syncthreads();                     // release wid1/wid2 after inv

            // h A-frags: plain coalesced dwordx4 (compiler hazard-tracked)
            const unsigned short* hsrc = hfm[p];
#pragma unroll
            for (int c = 0; c < 32; c += 2) {
                U8 a0; a0.d = *(const i32x4*)(hsrc + c * 512 + lane * 8);
                U8 a1; a1.d = *(const i32x4*)(hsrc + (c + 1) * 512 + lane * 8);
                acc2  = __builtin_amdgcn_mfma_f32_32x32x16_bf16(a0.b, Bf[16 + c].b,     acc2,  0, 0, 0);
                acc2b = __builtin_amdgcn_mfma_f32_32x32x16_bf16(a1.b, Bf[16 + c + 1].b, acc2b, 0, 0, 0);
            }
        }

        // fold split accumulators
#pragma unroll
        for (int i = 0; i < 16; ++i) { acc[i] += accB[i]; acc2[i] += acc2b[i]; }

        // gates: r,z waves publish to LDS; n wave does the update
        if (wid == 0) {
#pragma unroll
            for (int i = 0; i < 16; ++i) lds_r[p][i][lane] = sigm(acc[i] + acc2[i]);
        } else if (wid == 1) {
#pragma unroll
            for (int i = 0; i < 16; ++i) lds_z[p][i][lane] = sigm(acc[i] + acc2[i]);
        }
        __syncthreads();
        if (wid == 2) {
            // dest: frag-major position of (row = bg*32+rr, col = sl*32+l31)
            unsigned short* sb = hfm[(t + 1) & 1]
                               + (sl * 2 + (l31 >> 4)) * 512
                               + ((l31 >> 3) & 1) * 256 + (l31 & 7);
#pragma unroll
            for (int i = 0; i < 16; ++i) {
                float r = lds_r[p][i][lane];
                float z = lds_z[p][i][lane];
                float n = tanh_f(acc[i] + r * acc2[i]);   // xn + r*(hn+b_hh_n)
                float hn = (1.f - z) * n + z * hold[i];
                hold[i] = hn;
                int rr = (i & 3) + 8 * (i >> 2) + 4 * lh;  // C/D row map
                __hip_atomic_store(sb + rr * 8, f2bf(hn), __ATOMIC_RELAXED, AGENT);
            }
            // all h stores acked at the coherence point before the flag store
            asm volatile("s_waitcnt vmcnt(0)" ::: "memory");
            if (lane == 0)
                __hip_atomic_store(fmine, (unsigned)(t + 1), __ATOMIC_RELAXED, AGENT);
        }
    }
}

// ---------------- FC head: out[b] = sigmoid(concat(h_f,h_b) . fc_w + fc_b) ----
__global__ void fc_k(const unsigned short* __restrict__ hbuf,
                     const float* __restrict__ fcw, const float* __restrict__ fcb,
                     float* __restrict__ out) {
    int bb = blockIdx.x;
    int l = threadIdx.x;       // 64 threads = 1 wave
    int bg = bb >> 5, rr = bb & 31;
    float s = 0.f;
    for (int col = l; col < H_; col += 64) {
        int c = col >> 4, hi = (col >> 3) & 1, j = col & 7;
        int off = c * 512 + (hi * 32 + rr) * 8 + j;
        s += bf2f(hbuf[hfm_base(0, 0, bg) + off]) * fcw[col];        // fwd, buf 0
        s += bf2f(hbuf[hfm_base(1, 0, bg) + off]) * fcw[H_ + col];   // bwd, buf 0
    }
#pragma unroll
    for (int o = 32; o > 0; o >>= 1) s += __shfl_down(s, o);
    if (l == 0) out[bb] = sigm(s + fcb[0]);
}

extern "C" void kernel_launch(void* const* d_in, const int* in_sizes, int n_in,
                              void* d_out, int out_size, void* d_ws, size_t ws_size,
                              hipStream_t stream) {
    (void)in_sizes; (void)n_in; (void)out_size; (void)ws_size;
    const int*   inputs = (const int*)d_in[0];
    const float* emb    = (const float*)d_in[1];
    const float* Wih_f  = (const float*)d_in[2];
    const float* Whh_f  = (const float*)d_in[3];
    const float* bih_f  = (const float*)d_in[4];
    const float* bhh_f  = (const float*)d_in[5];
    const float* Wih_b  = (const float*)d_in[6];
    const float* Whh_b  = (const float*)d_in[7];
    const float* bih_b  = (const float*)d_in[8];
    const float* bhh_b  = (const float*)d_in[9];
    const float* fcw    = (const float*)d_in[10];
    const float* fcb    = (const float*)d_in[11];
    float* out = (float*)d_out;

    char* w = (char*)d_ws;
    unsigned short* xbuf = (unsigned short*)w;                          // 33,554,432 B
    unsigned short* hbuf = (unsigned short*)(w + 33554432);             //    524,288 B
    unsigned int*   flags= (unsigned int*)(w + 33554432 + 524288);      //      8,192 B

    hipMemsetAsync(flags, 0, 2 * NBG * 16 * 64, stream);
    gather_k<<<B_ * T_, E_, 0, stream>>>(inputs, emb, xbuf);
    gru_k<<<128, 192, 0, stream>>>(xbuf, Wih_f, Whh_f, bih_f, bhh_f,
                                   Wih_b, Whh_b, bih_b, bhh_b, hbuf, flags);
    fc_k<<<B_, 64, 0, stream>>>(hbuf, fcw, fcb, out);
}